// Round 4
// baseline (2074.888 us; speedup 1.0000x reference)
//
#include <hip/hip_runtime.h>
#include <math.h>

#define BB 256
#define TT 2048
#define HH 64

typedef _Float16 half2v __attribute__((ext_vector_type(2)));
typedef __fp16  fp16v2 __attribute__((ext_vector_type(2)));
union H2I { half2v h; int i; };

#if __has_builtin(__builtin_amdgcn_rcpf)
__device__ __forceinline__ float fast_rcp(float v) { return __builtin_amdgcn_rcpf(v); }
#else
__device__ __forceinline__ float fast_rcp(float v) { return 1.0f / v; }
#endif
#if __has_builtin(__builtin_amdgcn_rsqf)
__device__ __forceinline__ float fast_rsq(float v) { return __builtin_amdgcn_rsqf(v); }
#else
__device__ __forceinline__ float fast_rsq(float v) { return rsqrtf(v); }
#endif

__device__ __forceinline__ float tanh_fast(float v) {
    // tanh(x) = 1 - 2/(e^{2x}+1); saturates correctly at +/-inf
    float e = __expf(2.0f * v);
    return fmaf(-2.0f, fast_rcp(e + 1.0f), 1.0f);
}

__device__ __forceinline__ float sigmoid_fast(float v) {
    return fast_rcp(1.0f + __expf(-v));
}

__device__ __forceinline__ float fdot2(half2v a, half2v b, float c) {
    return __builtin_amdgcn_fdot2(a, b, c, false);
}

__device__ __forceinline__ half2v pack_pair(float a, float b) {
    fp16v2 r = __builtin_amdgcn_cvt_pkrtz(a, b);
    return __builtin_bit_cast(half2v, r);
}

// force a value to live in a VGPR (defeat load-rematerialization)
__device__ __forceinline__ void pin_h2(half2v& v) {
    H2I u; u.h = v;
    asm volatile("" : "+v"(u.i));
    v = u.h;
}

// dot2 with HARD VGPR constraints: weight operand must be an arch VGPR at use.
// Keeping the weight in an AGPR would force the allocator to emit a copy per
// use -> biases allocation to arch VGPRs (the round-4 experiment).
__device__ __forceinline__ void dot_v(float& acc, int s, half2v w) {
    H2I u; u.h = w;
    asm("v_dot2_f32_f16 %0, %1, %2, %0" : "+v"(acc) : "v"(s), "v"(u.i));
}

// broadcast packed f16x2 from a wave-uniform lane (result -> SGPR)
__device__ __forceinline__ int bcast_i(half2v v, int lane) {
    H2I u; u.h = v;
    return __builtin_amdgcn_readlane(u.i, lane);
}

// neighbor value within a quad: lane j gets lane j^1 (DPP quad_perm [1,0,3,2])
__device__ __forceinline__ float dpp_neighbor(float v) {
    return __int_as_float(__builtin_amdgcn_mov_dpp(__float_as_int(v), 0xB1, 0xf, 0xf, true));
}

__global__ __launch_bounds__(64, 1)
void pgjanet_kernel(const float* __restrict__ x,
                    const float* __restrict__ h0,
                    const float* __restrict__ Wa,  const float* __restrict__ ba,
                    const float* __restrict__ Wp1, const float* __restrict__ bp1,
                    const float* __restrict__ Wp2, const float* __restrict__ bp2,
                    const float* __restrict__ Wf,  const float* __restrict__ bf,
                    const float* __restrict__ Wg,  const float* __restrict__ bg,
                    const float* __restrict__ Wo,  const float* __restrict__ bo,
                    float* __restrict__ out)
{
    const int b = blockIdx.x;
    const int j = threadIdx.x;   // 0..63 : hidden index, single wave per block

    __shared__ float xs[TT * 2];            // 16 KB staged input
    __shared__ float hbuf[64][HH + 1];      // h-history ring; stride 65 -> conflict-free
    __shared__ float woLDS[2 * HH];         // Wo staged for broadcast reads in flush
    __shared__ unsigned int wgls[64 * 34];  // Wg u-part, packed fp16 pairs; stride 34 -> 2-way (free)

    // ---- stage x (coalesced float4), Wo ----
    {
        const float4* xp4 = reinterpret_cast<const float4*>(x + (size_t)b * (TT * 2));
        float4*       xs4 = reinterpret_cast<float4*>(xs);
#pragma unroll
        for (int i = 0; i < (TT * 2 / 4) / 64; ++i) xs4[j + 64 * i] = xp4[j + 64 * i];
    }
    for (int i = j; i < 2 * HH; i += 64) woLDS[i] = Wo[i];

    // ---- persistent register weights: 160 (w5) + 32 (wfu) = 192 arch VGPRs ----
    // w5: a, p1, p2, f_h, g_h (h-part);  wfu: u-part of Wf
    half2v w5[5][32], wfu[32];
    {
        const float* Wsrc[5] = {Wa, Wp1, Wp2, Wf, Wg};
        const int    ldv[5]  = {HH + 1, HH + 1, HH + 1, 2 * HH, 2 * HH};
#pragma unroll
        for (int g = 0; g < 5; ++g) {
            const float* r = Wsrc[g] + (size_t)j * ldv[g];
#pragma unroll
            for (int m = 0; m < 32; ++m) w5[g][m] = pack_pair(r[2 * m], r[2 * m + 1]);
        }
        const float* rf = Wf + (size_t)j * (2 * HH) + HH;
#pragma unroll
        for (int m = 0; m < 32; ++m) wfu[m] = pack_pair(rf[2 * m], rf[2 * m + 1]);
#pragma unroll
        for (int g = 0; g < 5; ++g)
#pragma unroll
            for (int m = 0; m < 32; ++m) pin_h2(w5[g][m]);
#pragma unroll
        for (int m = 0; m < 32; ++m) pin_h2(wfu[m]);
    }
    // ---- Wg u-part packed into LDS (re-read per step in small batches) ----
    {
        const float* rg = Wg + (size_t)j * (2 * HH) + HH;
#pragma unroll
        for (int m = 0; m < 32; ++m) {
            H2I t; t.h = pack_pair(rg[2 * m], rg[2 * m + 1]);
            wgls[j * 34 + m] = (unsigned int)t.i;
        }
    }

    const float waX  = Wa [j * (HH + 1) + HH];
    const float wp1X = Wp1[j * (HH + 1) + HH];
    const float wp2X = Wp2[j * (HH + 1) + HH];
    const float ba_r = ba[j], bp1_r = bp1[j], bp2_r = bp2[j];
    const float bf_r = bf[j], bg_r = bg[j];
    const float bo0  = bo[0], bo1 = bo[1];

    float  h  = h0[b * HH + j];
    float* yp = out + (size_t)b * (TT * 2);

    __syncthreads();   // single wave: near-free; orders staging

    // x-scalar pipeline for t=0 (amp/cos/sin via one rsq)
    float amp, ct, st;
    {
        float xi = xs[0], xq = xs[1];
        float r2 = xi * xi + xq * xq;
        float rq = fast_rsq(r2);
        bool ok = r2 > 0.f;
        amp = ok ? r2 * rq : 0.f;
        ct  = ok ? xi * rq : 1.f;   // cos(atan2(q,i)); atan2(0,0)=0
        st  = ok ? xq * rq : 0.f;
    }

    const unsigned int* wrow = &wgls[j * 34];

    for (int t = 0; t < TT; ++t) {
        // h broadcast prep
        float  hnbr = dpp_neighbor(h);
        half2v hp   = pack_pair(h, hnbr);

        // next step's x scalars (independent: fills latency slots)
        const int tn = (t + 1 < TT) ? (t + 1) : t;
        float xi_n = xs[2 * tn], xq_n = xs[2 * tn + 1];
        float amp_n, ct_n, st_n;
        {
            float r2 = xi_n * xi_n + xq_n * xq_n;
            float rq = fast_rsq(r2);
            bool ok = r2 > 0.f;
            amp_n = ok ? r2 * rq : 0.f;
            ct_n  = ok ? xi_n * rq : 1.f;
            st_n  = ok ? xq_n * rq : 0.f;
        }

        // ---- phase A: 5 h-matvecs, 10 accumulator chains (16-deep), asm dots ----
        float A0 = fmaf(amp, waX,  ba_r);
        float A1 = fmaf(ct,  wp1X, bp1_r);
        float A2 = fmaf(st,  wp2X, bp2_r);
        float A3 = bf_r;
        float A4 = bg_r;
        float B0 = 0.f, B1 = 0.f, B2 = 0.f, B3 = 0.f, B4 = 0.f;
#pragma unroll
        for (int m = 0; m < 16; ++m) {
            int slo = bcast_i(hp, 2 * m);
            int shi = bcast_i(hp, 2 * (m + 16));
            dot_v(A0, slo, w5[0][m]);
            dot_v(A1, slo, w5[1][m]);
            dot_v(A2, slo, w5[2][m]);
            dot_v(A3, slo, w5[3][m]);
            dot_v(A4, slo, w5[4][m]);
            dot_v(B0, shi, w5[0][m + 16]);
            dot_v(B1, shi, w5[1][m + 16]);
            dot_v(B2, shi, w5[2][m + 16]);
            dot_v(B3, shi, w5[3][m + 16]);
            dot_v(B4, shi, w5[4][m + 16]);
        }
        float acc0 = A0 + B0, acc1 = A1 + B1, acc2 = A2 + B2;
        float acc3 = A3 + B3, acc4 = A4 + B4;

        float av = tanh_fast(acc0);
        float p1 = tanh_fast(acc1);
        float p2 = tanh_fast(acc2);
        // u = a(1-a) * p1(1-p1) * p2(1-p2)
        float u = fmaf(-av, av, av) * fmaf(-p1, p1, p1) * fmaf(-p2, p2, p2);

        float  unbr = dpp_neighbor(u);
        half2v up   = pack_pair(u, unbr);

        // u broadcast -> wave-uniform ints (SGPRs)
        int su[32];
#pragma unroll
        for (int m = 0; m < 32; ++m) su[m] = bcast_i(up, 2 * m);

        // ---- f-dots (register weights, asm), 2 chains 16-deep ----
        float f0 = acc3, f1 = 0.f;
#pragma unroll
        for (int m = 0; m < 16; ++m) {
            dot_v(f0, su[m],      wfu[m]);
            dot_v(f1, su[m + 16], wfu[m + 16]);
        }

        // ---- g-dots (LDS weights, ping-pong 4-pair batches: 16 transient VGPRs) ----
        float g0 = acc4, g1 = 0.f;
        {
            uint2 wb[2][2];
            wb[0][0] = *reinterpret_cast<const uint2*>(&wrow[0]);
            wb[0][1] = *reinterpret_cast<const uint2*>(&wrow[2]);
#pragma unroll
            for (int bch = 0; bch < 8; ++bch) {
                const int cur = bch & 1, nxt = cur ^ 1;
                if (bch < 7) {
                    wb[nxt][0] = *reinterpret_cast<const uint2*>(&wrow[4 * (bch + 1)]);
                    wb[nxt][1] = *reinterpret_cast<const uint2*>(&wrow[4 * (bch + 1) + 2]);
                }
                H2I a0; a0.i = (int)wb[cur][0].x;
                H2I a1; a1.i = (int)wb[cur][0].y;
                H2I a2; a2.i = (int)wb[cur][1].x;
                H2I a3; a3.i = (int)wb[cur][1].y;
                H2I s0; s0.i = su[4 * bch];
                H2I s1; s1.i = su[4 * bch + 1];
                H2I s2; s2.i = su[4 * bch + 2];
                H2I s3; s3.i = su[4 * bch + 3];
                if (bch & 1) {
                    g1 = fdot2(s0.h, a0.h, g1);
                    g1 = fdot2(s1.h, a1.h, g1);
                    g1 = fdot2(s2.h, a2.h, g1);
                    g1 = fdot2(s3.h, a3.h, g1);
                } else {
                    g0 = fdot2(s0.h, a0.h, g0);
                    g0 = fdot2(s1.h, a1.h, g0);
                    g0 = fdot2(s2.h, a2.h, g0);
                    g0 = fdot2(s3.h, a3.h, g0);
                }
            }
        }

        float f = sigmoid_fast(f0 + f1);
        float g = tanh_fast(g0 + g1);
        h = fmaf(f, h - g, g);   // f*h + (1-f)*g

        // y deferred: 1 conflict-free ds_write per step into the ring
        hbuf[t & 63][j] = h;

        if ((t & 63) == 63) {
            // flush: lane L computes y(t-63+L) in f32; woLDS reads broadcast,
            // hbuf reads stride 65 words -> conflict-free
            float y0 = bo0, y1 = bo1;
#pragma unroll 4
            for (int k = 0; k < HH; ++k) {
                float hv = hbuf[j][k];
                y0 = fmaf(hv, woLDS[k],      y0);
                y1 = fmaf(hv, woLDS[HH + k], y1);
            }
            reinterpret_cast<float2*>(yp)[(t - 63) + j] = make_float2(y0, y1);
        }

        amp = amp_n; ct = ct_n; st = st_n;
    }
}

extern "C" void kernel_launch(void* const* d_in, const int* in_sizes, int n_in,
                              void* d_out, int out_size, void* d_ws, size_t ws_size,
                              hipStream_t stream) {
    const float* x   = (const float*)d_in[0];
    const float* h0  = (const float*)d_in[1];
    const float* Wa  = (const float*)d_in[2];
    const float* ba  = (const float*)d_in[3];
    const float* Wp1 = (const float*)d_in[4];
    const float* bp1 = (const float*)d_in[5];
    const float* Wp2 = (const float*)d_in[6];
    const float* bp2 = (const float*)d_in[7];
    const float* Wf  = (const float*)d_in[8];
    const float* bf  = (const float*)d_in[9];
    const float* Wg  = (const float*)d_in[10];
    const float* bg  = (const float*)d_in[11];
    const float* Wo  = (const float*)d_in[12];
    const float* bo  = (const float*)d_in[13];
    float* out = (float*)d_out;

    pgjanet_kernel<<<dim3(BB), dim3(64), 0, stream>>>(
        x, h0, Wa, ba, Wp1, bp1, Wp2, bp2, Wf, bf, Wg, bg, Wo, bo, out);
}

// Round 5
// 1586.289 us; speedup vs baseline: 1.3080x; 1.3080x over previous
//
#include <hip/hip_runtime.h>
#include <math.h>

#define BB 256
#define TT 2048
#define HH 64

typedef _Float16 half2v __attribute__((ext_vector_type(2)));
typedef __fp16  fp16v2 __attribute__((ext_vector_type(2)));
union H2I { half2v h; int i; };

#if __has_builtin(__builtin_amdgcn_rcpf)
__device__ __forceinline__ float fast_rcp(float v) { return __builtin_amdgcn_rcpf(v); }
#else
__device__ __forceinline__ float fast_rcp(float v) { return 1.0f / v; }
#endif
#if __has_builtin(__builtin_amdgcn_rsqf)
__device__ __forceinline__ float fast_rsq(float v) { return __builtin_amdgcn_rsqf(v); }
#else
__device__ __forceinline__ float fast_rsq(float v) { return rsqrtf(v); }
#endif

__device__ __forceinline__ float tanh_fast(float v) {
    // tanh(x) = 1 - 2/(e^{2x}+1); saturates correctly at +/-inf
    float e = __expf(2.0f * v);
    return fmaf(-2.0f, fast_rcp(e + 1.0f), 1.0f);
}

__device__ __forceinline__ float sigmoid_fast(float v) {
    return fast_rcp(1.0f + __expf(-v));
}

__device__ __forceinline__ float fdot2(half2v a, half2v b, float c) {
    return __builtin_amdgcn_fdot2(a, b, c, false);
}

__device__ __forceinline__ half2v pack_pair(float a, float b) {
    fp16v2 r = __builtin_amdgcn_cvt_pkrtz(a, b);
    return __builtin_bit_cast(half2v, r);
}

// force a value to live in a register (defeat load-rematerialization)
__device__ __forceinline__ void pin_h2(half2v& v) {
    H2I u; u.h = v;
    asm volatile("" : "+v"(u.i));
    v = u.h;
}

// broadcast packed f16x2 from a wave-uniform lane (result -> SGPR; dot reads it as the 1 allowed scalar operand)
__device__ __forceinline__ half2v bcast_pair(half2v v, int lane) {
    H2I u; u.h = v;
    H2I w; w.i = __builtin_amdgcn_readlane(u.i, lane);
    return w.h;
}

// neighbor value within a quad: lane j gets lane j^1 (DPP quad_perm [1,0,3,2])
__device__ __forceinline__ float dpp_neighbor(float v) {
    return __int_as_float(__builtin_amdgcn_mov_dpp(__float_as_int(v), 0xB1, 0xf, 0xf, true));
}

__global__ __launch_bounds__(128, 1)
void pgjanet_kernel(const float* __restrict__ x,
                    const float* __restrict__ h0,
                    const float* __restrict__ Wa,  const float* __restrict__ ba,
                    const float* __restrict__ Wp1, const float* __restrict__ bp1,
                    const float* __restrict__ Wp2, const float* __restrict__ bp2,
                    const float* __restrict__ Wf,  const float* __restrict__ bf,
                    const float* __restrict__ Wg,  const float* __restrict__ bg,
                    const float* __restrict__ Wo,  const float* __restrict__ bo,
                    float* __restrict__ out)
{
    const int b   = blockIdx.x;
    const int tid = threadIdx.x;
    const int j   = tid & 63;                                  // hidden index
    const int w   = __builtin_amdgcn_readfirstlane(tid >> 6);  // wave 0/1: K-half owner

    __shared__ float4 xt[TT];              // 32 KB: (amp, cos, sin, 0) per t
    __shared__ float  hbuf[64][HH + 1];    // 16.6 KB h ring; stride 65 -> conflict-free
    __shared__ float  woLDS[2 * HH];       // 0.5 KB
    __shared__ float2 exAB[2][2][2][64];   // [parity][wave][pairidx][lane] partial acc0/1, acc2/3
    __shared__ float  exC [2][2][64];      // [parity][wave][lane] partial acc4

    // ---- x-table: precompute amp/cos/sin once (removes per-step rsq/cndmask) ----
    for (int t = tid; t < TT; t += 128) {
        float2 xi = reinterpret_cast<const float2*>(x)[(size_t)b * TT + t];
        float r2 = xi.x * xi.x + xi.y * xi.y;
        float rq = fast_rsq(r2);
        bool ok = r2 > 0.f;
        xt[t] = make_float4(ok ? r2 * rq : 0.f,    // amp
                            ok ? xi.x * rq : 1.f,  // cos(atan2(q,i))
                            ok ? xi.y * rq : 0.f,  // sin
                            0.f);
    }
    for (int i = tid; i < 2 * HH; i += 128) woLDS[i] = Wo[i];

    // ---- weights: K-HALF of the 5 h-matvecs per wave; FULL u-parts of Wf/Wg ----
    half2v w5h[5][16], wfu[32], wgu[32];
    {
        const float* Wsrc[5] = {Wa, Wp1, Wp2, Wf, Wg};
        const int    ldv[5]  = {HH + 1, HH + 1, HH + 1, 2 * HH, 2 * HH};
#pragma unroll
        for (int g = 0; g < 5; ++g) {
            const float* r = Wsrc[g] + (size_t)j * ldv[g] + 32 * w;
#pragma unroll
            for (int m = 0; m < 16; ++m) w5h[g][m] = pack_pair(r[2 * m], r[2 * m + 1]);
        }
        const float* rf = Wf + (size_t)j * (2 * HH) + HH;
        const float* rg = Wg + (size_t)j * (2 * HH) + HH;
#pragma unroll
        for (int m = 0; m < 32; ++m) {
            wfu[m] = pack_pair(rf[2 * m], rf[2 * m + 1]);
            wgu[m] = pack_pair(rg[2 * m], rg[2 * m + 1]);
        }
#pragma unroll
        for (int g = 0; g < 5; ++g)
#pragma unroll
            for (int m = 0; m < 16; ++m) pin_h2(w5h[g][m]);
#pragma unroll
        for (int m = 0; m < 32; ++m) { pin_h2(wfu[m]); pin_h2(wgu[m]); }
    }

    const float waX  = Wa [j * (HH + 1) + HH];
    const float wp1X = Wp1[j * (HH + 1) + HH];
    const float wp2X = Wp2[j * (HH + 1) + HH];
    const float ba_r = ba[j], bp1_r = bp1[j], bp2_r = bp2[j];
    const float bf_r = bf[j], bg_r = bg[j];
    const float bo_w = (w == 0) ? bo[0] : bo[1];

    float h = h0[b * HH + j];

    __syncthreads();   // staging ready

    for (int t = 0; t < TT; ++t) {
        const int par = t & 1;
        float4 xv = xt[t];   // 1 ds_read_b128 (uniform addr -> broadcast)

        // h pair broadcast prep
        float  hnbr = dpp_neighbor(h);
        half2v hp   = pack_pair(h, hnbr);

        // ---- phase A partials: this wave's K-half of all 5 gates (80 dots) ----
        float p0 = 0.f, p1v = 0.f, p2v = 0.f, p3 = 0.f, p4 = 0.f;
#pragma unroll
        for (int m = 0; m < 16; ++m) {
            half2v s = bcast_pair(hp, 32 * w + 2 * m);
            p0  = fdot2(s, w5h[0][m], p0);
            p1v = fdot2(s, w5h[1][m], p1v);
            p2v = fdot2(s, w5h[2][m], p2v);
            p3  = fdot2(s, w5h[3][m], p3);
            p4  = fdot2(s, w5h[4][m], p4);
        }

        // ---- exchange partials: 3 writes, 1 barrier, 3 reads (parity-dbuf) ----
        exAB[par][w][0][j] = make_float2(p0, p1v);
        exAB[par][w][1][j] = make_float2(p2v, p3);
        exC [par][w][j]    = p4;
        __syncthreads();
        float2 o01 = exAB[par][w ^ 1][0][j];
        float2 o23 = exAB[par][w ^ 1][1][j];
        float  oc  = exC [par][w ^ 1][j];

        float acc0 = (p0  + o01.x) + fmaf(xv.x, waX,  ba_r);
        float acc1 = (p1v + o01.y) + fmaf(xv.y, wp1X, bp1_r);
        float acc2 = (p2v + o23.x) + fmaf(xv.z, wp2X, bp2_r);
        float acc3 = (p3  + o23.y) + bf_r;
        float acc4 = (p4  + oc)    + bg_r;

        // ---- duplicated tail (cheaper than a second exchange) ----
        float av = tanh_fast(acc0);
        float q1 = tanh_fast(acc1);
        float q2 = tanh_fast(acc2);
        float u = fmaf(-av, av, av) * fmaf(-q1, q1, q1) * fmaf(-q2, q2, q2);

        float  unbr = dpp_neighbor(u);
        half2v up   = pack_pair(u, unbr);

        // f/g u-dots: full K, 4 chains, broadcasts consumed immediately
        float f0 = acc3, f1 = 0.f, g0 = acc4, g1 = 0.f;
#pragma unroll
        for (int m = 0; m < 16; ++m) {
            half2v s0 = bcast_pair(up, 2 * m);
            half2v s1 = bcast_pair(up, 2 * (m + 16));
            f0 = fdot2(s0, wfu[m],      f0);
            f1 = fdot2(s1, wfu[m + 16], f1);
            g0 = fdot2(s0, wgu[m],      g0);
            g1 = fdot2(s1, wgu[m + 16], g1);
        }
        float f = sigmoid_fast(f0 + f1);
        float g = tanh_fast(g0 + g1);
        h = fmaf(f, h - g, g);   // f*h + (1-f)*g (identical in both waves)

        // y deferred: both waves write identical h (benign same-value store);
        // flush reads are ordered by each wave's own writes -> no barrier needed
        hbuf[t & 63][j] = h;

        if ((t & 63) == 63) {
            // lane j of wave w computes y(t-63+j), channel w, in f32
            const float* worow = &woLDS[w * HH];
            float y = bo_w;
#pragma unroll 4
            for (int k = 0; k < HH; ++k)
                y = fmaf(hbuf[j][k], worow[k], y);
            out[(size_t)b * (TT * 2) + 2 * ((t - 63) + j) + w] = y;
        }
    }
}

extern "C" void kernel_launch(void* const* d_in, const int* in_sizes, int n_in,
                              void* d_out, int out_size, void* d_ws, size_t ws_size,
                              hipStream_t stream) {
    const float* x   = (const float*)d_in[0];
    const float* h0  = (const float*)d_in[1];
    const float* Wa  = (const float*)d_in[2];
    const float* ba  = (const float*)d_in[3];
    const float* Wp1 = (const float*)d_in[4];
    const float* bp1 = (const float*)d_in[5];
    const float* Wp2 = (const float*)d_in[6];
    const float* bp2 = (const float*)d_in[7];
    const float* Wf  = (const float*)d_in[8];
    const float* bf  = (const float*)d_in[9];
    const float* Wg  = (const float*)d_in[10];
    const float* bg  = (const float*)d_in[11];
    const float* Wo  = (const float*)d_in[12];
    const float* bo  = (const float*)d_in[13];
    float* out = (float*)d_out;

    pgjanet_kernel<<<dim3(BB), dim3(128), 0, stream>>>(
        x, h0, Wa, ba, Wp1, bp1, Wp2, bp2, Wf, bf, Wg, bg, Wo, bo, out);
}

// Round 7
// 1513.552 us; speedup vs baseline: 1.3709x; 1.0481x over previous
//
#include <hip/hip_runtime.h>
#include <math.h>

#define BB 256
#define TT 2048
#define HH 64

typedef _Float16 half2v __attribute__((ext_vector_type(2)));
typedef __fp16  fp16v2 __attribute__((ext_vector_type(2)));
union H2I { half2v h; unsigned int i; };

#if __has_builtin(__builtin_amdgcn_rcpf)
__device__ __forceinline__ float fast_rcp(float v) { return __builtin_amdgcn_rcpf(v); }
#else
__device__ __forceinline__ float fast_rcp(float v) { return 1.0f / v; }
#endif
#if __has_builtin(__builtin_amdgcn_rsqf)
__device__ __forceinline__ float fast_rsq(float v) { return __builtin_amdgcn_rsqf(v); }
#else
__device__ __forceinline__ float fast_rsq(float v) { return rsqrtf(v); }
#endif

__device__ __forceinline__ float tanh_fast(float v) {
    // tanh(x) = 1 - 2/(e^{2x}+1); saturates correctly at +/-inf
    float e = __expf(2.0f * v);
    return fmaf(-2.0f, fast_rcp(e + 1.0f), 1.0f);
}

__device__ __forceinline__ float sigmoid_fast(float v) {
    return fast_rcp(1.0f + __expf(-v));
}

__device__ __forceinline__ float fdot2(half2v a, half2v b, float c) {
    return __builtin_amdgcn_fdot2(a, b, c, false);
}

__device__ __forceinline__ half2v pack_pair(float a, float b) {
    fp16v2 r = __builtin_amdgcn_cvt_pkrtz(a, b);
    return __builtin_bit_cast(half2v, r);
}

// force a value to live in a register (defeat load-rematerialization)
__device__ __forceinline__ void pin_h2(half2v& v) {
    H2I u; u.h = v;
    asm volatile("" : "+v"(u.i));
    v = u.h;
}

// neighbor value within a quad: lane j gets lane j^1 (DPP quad_perm [1,0,3,2])
__device__ __forceinline__ float dpp_neighbor(float v) {
    return __int_as_float(__builtin_amdgcn_mov_dpp(__float_as_int(v), 0xB1, 0xf, 0xf, true));
}

__device__ __forceinline__ half2v h2_from_u32(unsigned int w) {
    H2I u; u.i = w;
    return u.h;
}

__global__ __launch_bounds__(64, 1)
void pgjanet_kernel(const float* __restrict__ x,
                    const float* __restrict__ h0,
                    const float* __restrict__ Wa,  const float* __restrict__ ba,
                    const float* __restrict__ Wp1, const float* __restrict__ bp1,
                    const float* __restrict__ Wp2, const float* __restrict__ bp2,
                    const float* __restrict__ Wf,  const float* __restrict__ bf,
                    const float* __restrict__ Wg,  const float* __restrict__ bg,
                    const float* __restrict__ Wo,  const float* __restrict__ bo,
                    float* __restrict__ out)
{
    const int b = blockIdx.x;
    const int j = threadIdx.x;   // 0..63 : hidden index, single wave per block

    __shared__ float4 xt[TT];                         // 32 KB: (amp, cos, sin, 0) per t
    __shared__ float  hbuf[64][HH + 1];               // 16.6 KB h ring; stride 65 -> conflict-free
    __shared__ float  woLDS[2 * HH];                  // 0.5 KB
    __shared__ __align__(16) unsigned int hpk[32];    // packed h pairs (broadcast source)
    __shared__ __align__(16) unsigned int upk[32];    // packed u pairs

    // ---- x-table: precompute amp/cos/sin once (removes per-step rsq/cndmask) ----
    for (int t = j; t < TT; t += 64) {
        float2 xi = reinterpret_cast<const float2*>(x)[(size_t)b * TT + t];
        float r2 = xi.x * xi.x + xi.y * xi.y;
        float rq = fast_rsq(r2);
        bool ok = r2 > 0.f;
        xt[t] = make_float4(ok ? r2 * rq : 0.f,    // amp
                            ok ? xi.x * rq : 1.f,  // cos(atan2(q,i))
                            ok ? xi.y * rq : 0.f,  // sin
                            0.f);
    }
    for (int i = j; i < 2 * HH; i += 64) woLDS[i] = Wo[i];

    // ---- all weights in-register (AGPR parking is fine on gfx950 unified file) ----
    half2v w5[5][32], wfu[32], wgu[32];
    {
        const float* Wsrc[5] = {Wa, Wp1, Wp2, Wf, Wg};
        const int    ldv[5]  = {HH + 1, HH + 1, HH + 1, 2 * HH, 2 * HH};
#pragma unroll
        for (int g = 0; g < 5; ++g) {
            const float* r = Wsrc[g] + (size_t)j * ldv[g];
#pragma unroll
            for (int m = 0; m < 32; ++m) w5[g][m] = pack_pair(r[2 * m], r[2 * m + 1]);
        }
        const float* rf = Wf + (size_t)j * (2 * HH) + HH;
        const float* rg = Wg + (size_t)j * (2 * HH) + HH;
#pragma unroll
        for (int m = 0; m < 32; ++m) {
            wfu[m] = pack_pair(rf[2 * m], rf[2 * m + 1]);
            wgu[m] = pack_pair(rg[2 * m], rg[2 * m + 1]);
        }
#pragma unroll
        for (int g = 0; g < 5; ++g)
#pragma unroll
            for (int m = 0; m < 32; ++m) pin_h2(w5[g][m]);
#pragma unroll
        for (int m = 0; m < 32; ++m) { pin_h2(wfu[m]); pin_h2(wgu[m]); }
    }

    const float waX  = Wa [j * (HH + 1) + HH];
    const float wp1X = Wp1[j * (HH + 1) + HH];
    const float wp2X = Wp2[j * (HH + 1) + HH];
    const float ba_r = ba[j], bp1_r = bp1[j], bp2_r = bp2[j];
    const float bf_r = bf[j], bg_r = bg[j];
    const float bo0  = bo[0], bo1 = bo[1];

    float  h  = h0[b * HH + j];
    float* yp = out + (size_t)b * (TT * 2);

    __syncthreads();   // single wave: near-free; orders staging

    float4 xv = xt[0];

    for (int t = 0; t < TT; ++t) {
        // prefetch next step's x scalars (uniform ds_read_b128; used next iter)
        const int tn = (t + 1 < TT) ? (t + 1) : t;
        float4 xv_n = xt[tn];

        // ---- h broadcast via LDS: pack pair, even lanes write, all lanes read b128 ----
        {
            float hn = dpp_neighbor(h);
            H2I hp; hp.h = pack_pair(h, hn);   // even lane j: (h_j, h_{j+1})
            if ((j & 1) == 0) hpk[j >> 1] = hp.i;
        }
        uint4 hw[8];
#pragma unroll
        for (int i = 0; i < 8; ++i) hw[i] = reinterpret_cast<const uint4*>(hpk)[i];

        // ---- phase A: 5 h-matvecs, 5 chains, operands straight from LDS-broadcast regs ----
        float acc0 = fmaf(xv.x, waX,  ba_r);
        float acc1 = fmaf(xv.y, wp1X, bp1_r);
        float acc2 = fmaf(xv.z, wp2X, bp2_r);
        float acc3 = bf_r;
        float acc4 = bg_r;
#pragma unroll
        for (int i = 0; i < 8; ++i) {
#pragma unroll
            for (int q = 0; q < 4; ++q) {
                const int m = 4 * i + q;
                half2v s = h2_from_u32((&hw[i].x)[q]);
                acc0 = fdot2(s, w5[0][m], acc0);
                acc1 = fdot2(s, w5[1][m], acc1);
                acc2 = fdot2(s, w5[2][m], acc2);
                acc3 = fdot2(s, w5[3][m], acc3);
                acc4 = fdot2(s, w5[4][m], acc4);
            }
        }

        float av = tanh_fast(acc0);
        float p1 = tanh_fast(acc1);
        float p2 = tanh_fast(acc2);
        // u = a(1-a) * p1(1-p1) * p2(1-p2)
        float u = fmaf(-av, av, av) * fmaf(-p1, p1, p1) * fmaf(-p2, p2, p2);

        // ---- u broadcast via LDS (same pattern) ----
        {
            float un = dpp_neighbor(u);
            H2I up; up.h = pack_pair(u, un);
            if ((j & 1) == 0) upk[j >> 1] = up.i;
        }
        uint4 uw[8];
#pragma unroll
        for (int i = 0; i < 8; ++i) uw[i] = reinterpret_cast<const uint4*>(upk)[i];

        // ---- phase C: f,g u-dots, 4 chains ----
        float f0 = acc3, f1 = 0.f, g0 = acc4, g1 = 0.f;
#pragma unroll
        for (int i = 0; i < 4; ++i) {
#pragma unroll
            for (int q = 0; q < 4; ++q) {
                const int m  = 4 * i + q;        // 0..15
                const int m2 = m + 16;           // 16..31
                half2v s0 = h2_from_u32((&uw[i].x)[q]);
                half2v s1 = h2_from_u32((&uw[i + 4].x)[q]);
                f0 = fdot2(s0, wfu[m],  f0);
                f1 = fdot2(s1, wfu[m2], f1);
                g0 = fdot2(s0, wgu[m],  g0);
                g1 = fdot2(s1, wgu[m2], g1);
            }
        }
        float f = sigmoid_fast(f0 + f1);
        float g = tanh_fast(g0 + g1);
        h = fmaf(f, h - g, g);   // f*h + (1-f)*g

        // y deferred: 1 conflict-free ds_write per step into the ring
        hbuf[t & 63][j] = h;

        if ((t & 63) == 63) {
            // flush: lane L computes y(t-63+L) in f32; woLDS reads broadcast,
            // hbuf reads stride 65 words -> conflict-free
            float y0 = bo0, y1 = bo1;
#pragma unroll 4
            for (int k = 0; k < HH; ++k) {
                float hv = hbuf[j][k];
                y0 = fmaf(hv, woLDS[k],      y0);
                y1 = fmaf(hv, woLDS[HH + k], y1);
            }
            reinterpret_cast<float2*>(yp)[(t - 63) + j] = make_float2(y0, y1);
        }

        xv = xv_n;
    }
}

extern "C" void kernel_launch(void* const* d_in, const int* in_sizes, int n_in,
                              void* d_out, int out_size, void* d_ws, size_t ws_size,
                              hipStream_t stream) {
    const float* x   = (const float*)d_in[0];
    const float* h0  = (const float*)d_in[1];
    const float* Wa  = (const float*)d_in[2];
    const float* ba  = (const float*)d_in[3];
    const float* Wp1 = (const float*)d_in[4];
    const float* bp1 = (const float*)d_in[5];
    const float* Wp2 = (const float*)d_in[6];
    const float* bp2 = (const float*)d_in[7];
    const float* Wf  = (const float*)d_in[8];
    const float* bf  = (const float*)d_in[9];
    const float* Wg  = (const float*)d_in[10];
    const float* bg  = (const float*)d_in[11];
    const float* Wo  = (const float*)d_in[12];
    const float* bo  = (const float*)d_in[13];
    float* out = (float*)d_out;

    pgjanet_kernel<<<dim3(BB), dim3(64), 0, stream>>>(
        x, h0, Wa, ba, Wp1, bp1, Wp2, bp2, Wf, bf, Wg, bg, Wo, bo, out);
}